// Round 14
// baseline (104.973 us; speedup 1.0000x reference)
//
#include <hip/hip_runtime.h>
#include <cstdint>
#include <cstddef>

typedef unsigned short u16;
typedef __bf16 bf16x8 __attribute__((ext_vector_type(8)));
typedef __bf16 bf16x2 __attribute__((ext_vector_type(2)));
typedef float f32x4 __attribute__((ext_vector_type(4)));
typedef float f32x16 __attribute__((ext_vector_type(16)));

#define DEV __device__ __forceinline__

DEV float bf2f(u16 v) { union { unsigned u; float f; } x; x.u = ((unsigned)v) << 16; return x.f; }
DEV u16 f2bf(float f) {
  union { float f; unsigned u; } x; x.f = f;
  unsigned u = x.u + 0x7fffu + ((x.u >> 16) & 1u);
  return (u16)(u >> 16);
}

DEV float fexp2(float x) {
#if __has_builtin(__builtin_amdgcn_exp2f)
  return __builtin_amdgcn_exp2f(x);
#else
  return exp2f(x);
#endif
}

DEV f32x4 mfma16(bf16x8 a, bf16x8 b, f32x4 c) {
  return __builtin_amdgcn_mfma_f32_16x16x32_bf16(a, b, c, 0, 0, 0);
}
DEV f32x16 mfma32(bf16x8 a, bf16x8 b, f32x16 c) {
  return __builtin_amdgcn_mfma_f32_32x32x16_bf16(a, b, c, 0, 0, 0);
}

DEV void stage16(const void* g, void* l) {
#if __has_builtin(__builtin_amdgcn_global_load_lds)
  __builtin_amdgcn_global_load_lds((__attribute__((address_space(1))) void*)g,
                                   (__attribute__((address_space(3))) void*)l, 16, 0, 0);
#else
  *(uint4*)l = *(const uint4*)g;
#endif
}

DEV unsigned pkbf(float a, float b) {
  bf16x2 v = {(__bf16)a, (__bf16)b};
  return __builtin_bit_cast(unsigned, v);
}

// v_permlane32_swap_b32 (orientation verified R3-R5)
DEV void plswap(unsigned& a, unsigned& b) {
#if __has_builtin(__builtin_amdgcn_permlane32_swap)
  auto r = __builtin_amdgcn_permlane32_swap(a, b, false, false);
  a = (unsigned)r[0];
  b = (unsigned)r[1];
#else
  unsigned sa = __shfl_xor((int)a, 32), sb = __shfl_xor((int)b, 32);
  bool hi = ((threadIdx.x & 63) >> 5) != 0;
  unsigned na = hi ? sb : a;
  unsigned nb = hi ? b : sa;
  a = na; b = nb;
#endif
}

// ---------------- fp32->bf16 conversions + RoPE cos/sin table ----------------
__global__ __launch_bounds__(256) void cvt_all(const float* __restrict__ x,
                                               const float* __restrict__ Wq,
                                               const float* __restrict__ Wkv,
                                               const float* __restrict__ Wo,
                                               u16* __restrict__ xb,
                                               u16* __restrict__ wqkv,
                                               u16* __restrict__ wo,
                                               float2* __restrict__ tab) {
  const int blk = blockIdx.x;
  if (blk >= 7168) {   // 256 blocks: 65536-entry rope table (pos 0..2047 x fi 0..31)
    const int idx = (blk - 7168) * 256 + threadIdx.x;
    const int pos = idx >> 5, fi = idx & 31;
    float ang = (float)pos * exp2f((float)fi * -0.415241011860919f);
    float sn, cs;
    sincosf(ang, &sn, &cs);
    tab[idx] = make_float2(cs, sn);
    return;
  }
  const float* src; u16* dst; int base;
  if (blk < 4096)      { src = x;   dst = xb;             base = blk; }
  else if (blk < 5120) { src = Wq;  dst = wqkv;           base = blk - 4096; }
  else if (blk < 6144) { src = Wkv; dst = wqkv + 1048576; base = blk - 5120; }
  else                 { src = Wo;  dst = wo;             base = blk - 6144; }
  const int i = (base * 256 + threadIdx.x) * 4;
  float4 v = *(const float4*)(src + i);
  ushort4 o;
  o.x = f2bf(v.x); o.y = f2bf(v.y); o.z = f2bf(v.z); o.w = f2bf(v.w);
  *(ushort4*)(dst + i) = o;
}

// ---------------- GEMM1 fused with RoPE + LayerNorm epilogue ----------------
// R14: 256x128 tile, 8 waves (4Mx2N), 512 thr, 96KB LDS, grid 256 (1 blk/CU).
// Halves LDS fragment-read bytes per output (LDS-BW was the post-swizzle
// wall). Counted vmcnt + raw barriers + T2 swizzle kept.
__global__ __launch_bounds__(512) void gemm_qkv(const u16* __restrict__ A,
                                                const u16* __restrict__ Bm,
                                                const float2* __restrict__ tab,
                                                const float* __restrict__ lng,
                                                const float* __restrict__ lnb,
                                                u16* __restrict__ q_b,
                                                u16* __restrict__ k_b,
                                                u16* __restrict__ vT_b) {
  __shared__ u16 As[2][16384];   // 256 rows x 64
  __shared__ u16 Bs[2][8192];    // 128 rows x 64
  const int tid = threadIdx.x;
  const int lane = tid & 63;
  const int lo = lane & 15, hi = lane >> 4;
  const int wid = tid >> 6;
  const int wr = wid >> 1, wc = wid & 1;      // 4M x 2N wave grid
  // XCD rect swizzle: 256 blocks = 16Mx16N tiles; XCD x owns 4Mx8N (4MB set)
  const int lin = blockIdx.x;
  const int xx = lin & 7, ii = lin >> 3;      // ii 0..31
  const int mt = ((xx & 3) << 2) | (ii >> 3); // 0..15
  const int nt = ((xx >> 2) << 3) | (ii & 7); // 0..15
  const long m0 = (long)mt * 256;
  const long n0 = (long)nt * 128;

  f32x4 acc[4][4];
  const f32x4 vzero = {0.f, 0.f, 0.f, 0.f};
#pragma unroll
  for (int i = 0; i < 4; ++i)
#pragma unroll
    for (int j = 0; j < 4; ++j) acc[i][j] = vzero;

  const char* Abase = (const char*)(A + m0 * 1024);
  const char* Bbase = (const char*)(Bm + n0 * 1024);

  // prologue: stage K-slab 0 (A: 4 chunks, B: 2 chunks; source pre-swizzled)
#pragma unroll
  for (int i = 0; i < 4; ++i) {
    int o = (i * 512 + tid) * 16;
    int row = o >> 7, kb = o & 127;
    int sc = kb ^ ((row & 7) << 4);
    stage16(Abase + (long)row * 2048 + sc, (char*)As[0] + o);
  }
#pragma unroll
  for (int i = 0; i < 2; ++i) {
    int o = (i * 512 + tid) * 16;
    int row = o >> 7, kb = o & 127;
    int sc = kb ^ ((row & 7) << 4);
    stage16(Bbase + (long)row * 2048 + sc, (char*)Bs[0] + o);
  }

  int cur = 0;
  for (int kt = 0; kt < 16; ++kt) {
    if (kt + 1 < 16) {
      const int kb0 = (kt + 1) * 128;
#pragma unroll
      for (int i = 0; i < 4; ++i) {
        int o = (i * 512 + tid) * 16;
        int row = o >> 7, kb = o & 127;
        int sc = kb ^ ((row & 7) << 4);
        stage16(Abase + (long)row * 2048 + kb0 + sc, (char*)As[cur ^ 1] + o);
      }
#pragma unroll
      for (int i = 0; i < 2; ++i) {
        int o = (i * 512 + tid) * 16;
        int row = o >> 7, kb = o & 127;
        int sc = kb ^ ((row & 7) << 4);
        stage16(Bbase + (long)row * 2048 + kb0 + sc, (char*)Bs[cur ^ 1] + o);
      }
      asm volatile("s_waitcnt vmcnt(6)" ::: "memory");
    } else {
      asm volatile("s_waitcnt vmcnt(0)" ::: "memory");
    }
    __builtin_amdgcn_s_barrier();
    __builtin_amdgcn_sched_barrier(0);
#pragma unroll
    for (int ks = 0; ks < 2; ++ks) {
      bf16x8 af[4], bfr[4];
#pragma unroll
      for (int mi = 0; mi < 4; ++mi) {
        const int row = wr * 64 + mi * 16 + lo;   // 0..255
        af[mi] = *(const bf16x8*)((const char*)As[cur] +
                                  ((row * 128 + ks * 64 + hi * 16) ^ ((row & 7) << 4)));
      }
#pragma unroll
      for (int ni = 0; ni < 4; ++ni) {
        const int row = wc * 64 + ni * 16 + lo;   // 0..127
        bfr[ni] = *(const bf16x8*)((const char*)Bs[cur] +
                                   ((row * 128 + ks * 64 + hi * 16) ^ ((row & 7) << 4)));
      }
#pragma unroll
      for (int mi = 0; mi < 4; ++mi)
#pragma unroll
        for (int ni = 0; ni < 4; ++ni)
          acc[mi][ni] = mfma16(af[mi], bfr[ni], acc[mi][ni]);
    }
    __builtin_amdgcn_sched_barrier(0);
    __builtin_amdgcn_s_barrier();
    cur ^= 1;
  }

  // ---- fused epilogue (wave col-span = 64 = one head) ----
  const int brow = mt >> 3;                   // 8 M-tiles per batch row
  const bool isQ = (nt < 8);
  const int h = (isQ ? nt * 2 : (nt - 8) * 2) + wc;
  const int bh = brow * 16 + h;
  float lg[4], lb[4];
  if (!isQ) {
#pragma unroll
    for (int ni = 0; ni < 4; ++ni) {
      lg[ni] = lng[ni * 16 + lo];
      lb[ni] = lnb[ni * 16 + lo];
    }
  }
#pragma unroll
  for (int mi = 0; mi < 4; ++mi) {
    const int pos0 = (mt & 7) * 256 + wr * 64 + mi * 16 + hi * 4;
    float cs[2][4], sn[2][4];
#pragma unroll
    for (int p = 0; p < 2; ++p)
#pragma unroll
      for (int r = 0; r < 4; ++r) {
        float2 t = tab[(pos0 + r) * 32 + p * 16 + lo];
        cs[p][r] = t.x; sn[p][r] = t.y;
      }
    float o[4][4];
#pragma unroll
    for (int ni = 0; ni < 4; ++ni) {
      const float sgn = (ni < 2) ? -1.f : 1.f;
#pragma unroll
      for (int r = 0; r < 4; ++r)
        o[ni][r] = acc[mi][ni][r] * cs[ni & 1][r] + sgn * acc[mi][ni ^ 2][r] * sn[ni & 1][r];
    }
    if (isQ) {
#pragma unroll
      for (int ni = 0; ni < 4; ++ni)
#pragma unroll
        for (int r = 0; r < 4; ++r)
          q_b[((size_t)bh * 2048 + pos0 + r) * 64 + ni * 16 + lo] =
              f2bf(o[ni][r] * 0.18033688f);   // SCALE*log2(e)
    } else {
      float s1[4], s2[4];
#pragma unroll
      for (int r = 0; r < 4; ++r) {
        s1[r] = o[0][r] + o[1][r] + o[2][r] + o[3][r];
        s2[r] = o[0][r] * o[0][r] + o[1][r] * o[1][r] + o[2][r] * o[2][r] + o[3][r] * o[3][r];
      }
#pragma unroll
      for (int msk = 1; msk < 16; msk <<= 1)
#pragma unroll
        for (int r = 0; r < 4; ++r) {
          s1[r] += __shfl_xor(s1[r], msk);
          s2[r] += __shfl_xor(s2[r], msk);
        }
      u16 kv16[4][4];
#pragma unroll
      for (int r = 0; r < 4; ++r) {
        const float mean = s1[r] * (1.f / 64.f);
        const float var = s2[r] * (1.f / 64.f) - mean * mean;
        const float rstd = rsqrtf(var + 1e-5f);
#pragma unroll
        for (int ni = 0; ni < 4; ++ni) {
          const float lk = (o[ni][r] - mean) * rstd * lg[ni] + lb[ni];
          kv16[ni][r] = f2bf(lk);
          k_b[((size_t)bh * 2048 + pos0 + r) * 64 + ni * 16 + lo] = kv16[ni][r];
        }
      }
#pragma unroll
      for (int ni = 0; ni < 4; ++ni) {
        ushort4 w4 = {kv16[ni][0], kv16[ni][1], kv16[ni][2], kv16[ni][3]};
        *(ushort4*)&vT_b[((size_t)bh * 64 + ni * 16 + lo) * 2048 + pos0] = w4;
      }
    }
  }
}

// ---------------- GEMM2: out = out_all @ Wo^T + bias (128x128 tile) ---------
// R14: 128x128 tile, grid 256 (1 blk/CU) — halves per-CU LDS fragment reads.
__global__ __launch_bounds__(256) void gemm_out(const u16* __restrict__ A,
                                                const u16* __restrict__ Bm,
                                                float* __restrict__ Cf,
                                                const float* __restrict__ bias) {
  __shared__ u16 As[2][8192];
  __shared__ u16 Bs[2][8192];
  const int tid = threadIdx.x;
  const int lane = tid & 63;
  const int lo = lane & 15, hi = lane >> 4;
  const int wid = tid >> 6;
  const int wr = wid >> 1, wc = wid & 1;
  // XCD rect swizzle: 256 blocks = 32Mx8N tiles; XCD x owns 8Mx4N (3MB set)
  const int lin = blockIdx.x;
  const int xx = lin & 7, ii = lin >> 3;
  const int mt = ((xx & 3) << 3) | (ii >> 2);  // 0..31
  const int nt = ((xx >> 2) << 2) | (ii & 3);  // 0..7
  const long m0 = (long)mt * 128;
  const long n0 = (long)nt * 128;

  f32x4 acc[4][4];
  const f32x4 vzero = {0.f, 0.f, 0.f, 0.f};
#pragma unroll
  for (int i = 0; i < 4; ++i)
#pragma unroll
    for (int j = 0; j < 4; ++j) acc[i][j] = vzero;

  const char* Abase = (const char*)(A + m0 * 1024);
  const char* Bbase = (const char*)(Bm + n0 * 1024);

#pragma unroll
  for (int i = 0; i < 4; ++i) {
    int o = (i * 256 + tid) * 16;
    int row = o >> 7, kb = o & 127;
    int sc = kb ^ ((row & 7) << 4);
    stage16(Abase + (long)row * 2048 + sc, (char*)As[0] + o);
    stage16(Bbase + (long)row * 2048 + sc, (char*)Bs[0] + o);
  }

  int cur = 0;
  for (int kt = 0; kt < 16; ++kt) {
    if (kt + 1 < 16) {
      const int kb0 = (kt + 1) * 128;
#pragma unroll
      for (int i = 0; i < 4; ++i) {
        int o = (i * 256 + tid) * 16;
        int row = o >> 7, kb = o & 127;
        int sc = kb ^ ((row & 7) << 4);
        stage16(Abase + (long)row * 2048 + kb0 + sc, (char*)As[cur ^ 1] + o);
        stage16(Bbase + (long)row * 2048 + kb0 + sc, (char*)Bs[cur ^ 1] + o);
      }
      asm volatile("s_waitcnt vmcnt(8)" ::: "memory");
    } else {
      asm volatile("s_waitcnt vmcnt(0)" ::: "memory");
    }
    __builtin_amdgcn_s_barrier();
    __builtin_amdgcn_sched_barrier(0);
#pragma unroll
    for (int ks = 0; ks < 2; ++ks) {
      bf16x8 af[4], bfr[4];
#pragma unroll
      for (int mi = 0; mi < 4; ++mi) {
        const int row = wr * 64 + mi * 16 + lo;
        af[mi] = *(const bf16x8*)((const char*)As[cur] +
                                  ((row * 128 + ks * 64 + hi * 16) ^ ((row & 7) << 4)));
      }
#pragma unroll
      for (int ni = 0; ni < 4; ++ni) {
        const int row = wc * 64 + ni * 16 + lo;
        bfr[ni] = *(const bf16x8*)((const char*)Bs[cur] +
                                   ((row * 128 + ks * 64 + hi * 16) ^ ((row & 7) << 4)));
      }
#pragma unroll
      for (int mi = 0; mi < 4; ++mi)
#pragma unroll
        for (int ni = 0; ni < 4; ++ni)
          acc[mi][ni] = mfma16(af[mi], bfr[ni], acc[mi][ni]);
    }
    __builtin_amdgcn_sched_barrier(0);
    __builtin_amdgcn_s_barrier();
    cur ^= 1;
  }
#pragma unroll
  for (int mi = 0; mi < 4; ++mi)
#pragma unroll
    for (int ni = 0; ni < 4; ++ni) {
      const long col = n0 + wc * 64 + ni * 16 + lo;
      const float bs = bias[col];
#pragma unroll
      for (int r = 0; r < 4; ++r) {
        const long row = m0 + wr * 64 + mi * 16 + hi * 4 + r;
        Cf[row * 1024 + col] = acc[mi][ni][r] + bs;
      }
    }
}

// ---------------- fused flash attention (unchanged from R11) -----------------
__global__ __launch_bounds__(256, 2) void attn_kernel(const u16* __restrict__ q_b,
                                                      const u16* __restrict__ k_b,
                                                      const u16* __restrict__ vT_b,
                                                      u16* __restrict__ out_all) {
  __shared__ __align__(16) char smem[65536];
  __shared__ float ldsLs[2][2][32];
  __shared__ float ldsLi[2][2][32];
  const int tid = threadIdx.x;
  const int wid = tid >> 6, lane = tid & 63;
  const int l31 = lane & 31, lh = lane >> 5;
  const int half = wid >> 1, wp = wid & 1;
  const int bid = blockIdx.x;
  const int xcd = bid & 7, rest = bid >> 3;
  const int bh = (xcd << 2) | (rest & 3);
  const int unit = rest >> 2;
  const int b = bh >> 4, h = bh & 15;
  const bool lat = unit >= 12;
  const int q0b = lat ? 1536 + (unit - 12) * 128 : unit * 128;
  const int q0w = q0b + wp * 64;
  const int nkt_tot = lat ? ((q0b + 128) >> 6) : 24;
  const int nhalf = nkt_tot >> 1;
  const int kt0 = half * nhalf;
  const int wave_kmax = lat ? (q0w + 63) : 1535;
  const char* kg = (const char*)(k_b + (size_t)bh * 2048 * 64);
  const char* vg = (const char*)(vT_b + (size_t)bh * 64 * 2048);
  char* Kbuf0 = smem + half * 32768;
  char* Kbuf1 = Kbuf0 + 8192;
  char* Vbuf0 = Kbuf0 + 16384;
  char* Vbuf1 = Kbuf0 + 24576;
  const f32x16 vzero16 = {0.f,0.f,0.f,0.f,0.f,0.f,0.f,0.f,0.f,0.f,0.f,0.f,0.f,0.f,0.f,0.f};

  bf16x8 qf[2][4];
#pragma unroll
  for (int s = 0; s < 2; ++s) {
    const u16* qrow = q_b + ((size_t)bh * 2048 + q0w + s * 32 + l31) * 64;
#pragma unroll
    for (int ds = 0; ds < 4; ++ds)
      qf[s][ds] = *(const bf16x8*)(qrow + ds * 16 + lh * 8);
  }

  float lsum[2] = {0.f, 0.f};
  f32x16 oacc[2][2];
  oacc[0][0] = vzero16; oacc[0][1] = vzero16;
  oacc[1][0] = vzero16; oacc[1][1] = vzero16;

  const int t127 = tid & 127;

  {
    const int kb0 = kt0 << 6;
#pragma unroll
    for (int i = 0; i < 4; ++i) {
      const int off = t127 * 16 + i * 2048;
      const int row = off >> 7, colb = off & 127;
      const int sc = colb ^ ((row & 7) << 4);
      stage16(kg + (size_t)(kb0 + row) * 128 + sc, Kbuf0 + off);
      stage16(vg + (size_t)row * 4096 + (size_t)(kb0 << 1) + sc, Vbuf0 + off);
    }
  }

  for (int t = 0; t < nhalf; ++t) {
    const int kt = kt0 + t;
    const int k0 = kt << 6;
    const bool more = (t + 1 < nhalf);
    const char* Kc = (t & 1) ? Kbuf1 : Kbuf0;
    const char* Vc = (t & 1) ? Vbuf1 : Vbuf0;
    char* Kn = (t & 1) ? Kbuf0 : Kbuf1;
    char* Vn = (t & 1) ? Vbuf0 : Vbuf1;
    if (more) {
      const int k0n = k0 + 64;
#pragma unroll
      for (int i = 0; i < 4; ++i) {
        const int off = t127 * 16 + i * 2048;
        const int row = off >> 7, colb = off & 127;
        const int sc = colb ^ ((row & 7) << 4);
        stage16(kg + (size_t)(k0n + row) * 128 + sc, Kn + off);
        stage16(vg + (size_t)row * 4096 + (size_t)(k0n << 1) + sc, Vn + off);
      }
      asm volatile("s_waitcnt vmcnt(8)" ::: "memory");
    } else {
      asm volatile("s_waitcnt vmcnt(0)" ::: "memory");
    }
    __builtin_amdgcn_s_barrier();
    __builtin_amdgcn_sched_barrier(0);
    if (k0 <= wave_kmax) {
      const int sw = (l31 & 7) << 4;
      bf16x8 kfr[2][4];
      bf16x8 bv[4][2];
#pragma unroll
      for (int kb = 0; kb < 2; ++kb) {
        const char* kr = Kc + (kb * 32 + l31) * 128;
#pragma unroll
        for (int ds = 0; ds < 4; ++ds)
          kfr[kb][ds] = *(const bf16x8*)(kr + ((ds * 32 + lh * 16) ^ sw));
      }
#pragma unroll
      for (int db = 0; db < 2; ++db) {
        const char* vr = Vc + (db * 32 + l31) * 128;
#pragma unroll
        for (int t4 = 0; t4 < 4; ++t4)
          bv[t4][db] = *(const bf16x8*)(vr + ((t4 * 32 + lh * 16) ^ sw));
      }
      f32x16 s32[2][2];
      __builtin_amdgcn_s_setprio(1);
#pragma unroll
      for (int kb = 0; kb < 2; ++kb)
#pragma unroll
        for (int s = 0; s < 2; ++s) {
          f32x16 acc = vzero16;
#pragma unroll
          for (int ds = 0; ds < 4; ++ds)
            acc = mfma32(kfr[kb][ds], qf[s][ds], acc);
          s32[s][kb] = acc;
        }
      __builtin_amdgcn_s_setprio(0);
      unsigned w[2][16];
#pragma unroll
      for (int s = 0; s < 2; ++s) {
        if (lat && (k0 + 63 > q0w + s * 32)) {
          const int qg = q0w + s * 32 + l31;
#pragma unroll
          for (int kb = 0; kb < 2; ++kb)
#pragma unroll
            for (int r = 0; r < 16; ++r) {
              const int key = k0 + kb * 32 + (r & 3) + 8 * (r >> 2) + 4 * lh;
              if (key > qg) s32[s][kb][r] = -1e30f;
            }
        }
#pragma unroll
        for (int kb = 0; kb < 2; ++kb) {
          float p[16];
#pragma unroll
          for (int r = 0; r < 16; ++r) {
            p[r] = fexp2(s32[s][kb][r]);
            lsum[s] += p[r];
          }
#pragma unroll
          for (int m = 0; m < 8; ++m) w[s][kb * 8 + m] = pkbf(p[2 * m], p[2 * m + 1]);
        }
      }
#pragma unroll
      for (int t4 = 0; t4 < 4; ++t4) {
        const int g = t4 * 4;
        union { unsigned uw[4]; bf16x8 v; } A[2];
#pragma unroll
        for (int s = 0; s < 2; ++s) {
          plswap(w[s][g], w[s][g + 2]);
          plswap(w[s][g + 1], w[s][g + 3]);
          A[s].uw[0] = w[s][g];     A[s].uw[1] = w[s][g + 1];
          A[s].uw[2] = w[s][g + 2]; A[s].uw[3] = w[s][g + 3];
        }
        __builtin_amdgcn_s_setprio(1);
#pragma unroll
        for (int db = 0; db < 2; ++db) {
          oacc[0][db] = mfma32(A[0].v, bv[t4][db], oacc[0][db]);
          oacc[1][db] = mfma32(A[1].v, bv[t4][db], oacc[1][db]);
        }
        __builtin_amdgcn_s_setprio(0);
      }
    }
    __builtin_amdgcn_sched_barrier(0);
    __builtin_amdgcn_s_barrier();
  }

  float* mergeO = (float*)smem + (size_t)wp * 4096;
  if (half == 1) {
#pragma unroll
    for (int s = 0; s < 2; ++s) {
      float ls = lsum[s] + __shfl_xor(lsum[s], 32);
      if (lh == 0) ldsLs[wp][s][l31] = ls;
#pragma unroll
      for (int db = 0; db < 2; ++db)
#pragma unroll
        for (int r = 0; r < 16; ++r) {
          const int qv = (r & 3) + 8 * (r >> 2) + 4 * lh;
          mergeO[(s * 32 + qv) * 64 + db * 32 + l31] = oacc[s][db][r];
        }
    }
  }
  __syncthreads();
  if (half == 0) {
#pragma unroll
    for (int s = 0; s < 2; ++s) {
      float ls = lsum[s] + __shfl_xor(lsum[s], 32) + ldsLs[wp][s][l31];
      if (lh == 0) ldsLi[wp][s][l31] = 1.f / ls;
    }
    const int orow0 = lat ? (q0w - 1536) : (512 + q0w);
#pragma unroll
    for (int s = 0; s < 2; ++s)
#pragma unroll
      for (int db = 0; db < 2; ++db)
#pragma unroll
        for (int r = 0; r < 16; ++r) {
          const int qv = (r & 3) + 8 * (r >> 2) + 4 * lh;
          const float o = oacc[s][db][r] + mergeO[(s * 32 + qv) * 64 + db * 32 + l31];
          out_all[((size_t)b * 2048 + orow0 + s * 32 + qv) * 1024 + h * 64 + db * 32 + l31] =
              f2bf(o * ldsLi[wp][s][qv]);
        }
  }
}

extern "C" void kernel_launch(void* const* d_in, const int* in_sizes, int n_in,
                              void* d_out, int out_size, void* d_ws, size_t ws_size,
                              hipStream_t stream) {
  const float* x    = (const float*)d_in[0];
  const float* Wq   = (const float*)d_in[1];
  const float* Wkv  = (const float*)d_in[2];
  const float* Wo   = (const float*)d_in[3];
  const float* bo   = (const float*)d_in[4];
  const float* ln_g = (const float*)d_in[5];
  const float* ln_b = (const float*)d_in[6];
  float* out = (float*)d_out;
  char* ws = (char*)d_ws;

  u16*    xb      = (u16*)(ws + 0);                     // 8MB (dead after gemm_qkv)
  u16*    out_all = (u16*)(ws + 0);                     // 8MB (attn -> gemm_out)
  u16*    wqkv_b  = (u16*)(ws + (size_t)(8u << 20));    // 4MB
  u16*    wo_b    = (u16*)(ws + (size_t)(12u << 20));   // 2MB
  float2* tab     = (float2*)(ws + (size_t)(14u << 20));// 512KB rope table
  u16*    q_b     = (u16*)(ws + (size_t)(15u << 20));   // 8MB
  u16*    k_b     = (u16*)(ws + (size_t)(23u << 20));   // 8MB
  u16*    vT_b    = (u16*)(ws + (size_t)(31u << 20));   // 8MB

  cvt_all<<<7424, 256, 0, stream>>>(x, Wq, Wkv, Wo, xb, wqkv_b, wo_b, tab);
  gemm_qkv<<<256, 512, 0, stream>>>(xb, wqkv_b, tab, ln_g, ln_b,
                                    q_b, k_b, vT_b);
  attn_kernel<<<512, 256, 0, stream>>>(q_b, k_b, vT_b, out_all);
  gemm_out<<<256, 256, 0, stream>>>(out_all, wo_b, out, bo);
}

// Round 15
// 101.485 us; speedup vs baseline: 1.0344x; 1.0344x over previous
//
#include <hip/hip_runtime.h>
#include <cstdint>
#include <cstddef>

typedef unsigned short u16;
typedef __bf16 bf16x8 __attribute__((ext_vector_type(8)));
typedef __bf16 bf16x2 __attribute__((ext_vector_type(2)));
typedef float f32x4 __attribute__((ext_vector_type(4)));
typedef float f32x16 __attribute__((ext_vector_type(16)));

#define DEV __device__ __forceinline__

DEV float bf2f(u16 v) { union { unsigned u; float f; } x; x.u = ((unsigned)v) << 16; return x.f; }
DEV u16 f2bf(float f) {
  union { float f; unsigned u; } x; x.f = f;
  unsigned u = x.u + 0x7fffu + ((x.u >> 16) & 1u);
  return (u16)(u >> 16);
}

DEV float fexp2(float x) {
#if __has_builtin(__builtin_amdgcn_exp2f)
  return __builtin_amdgcn_exp2f(x);
#else
  return exp2f(x);
#endif
}

DEV f32x4 mfma16(bf16x8 a, bf16x8 b, f32x4 c) {
  return __builtin_amdgcn_mfma_f32_16x16x32_bf16(a, b, c, 0, 0, 0);
}
DEV f32x16 mfma32(bf16x8 a, bf16x8 b, f32x16 c) {
  return __builtin_amdgcn_mfma_f32_32x32x16_bf16(a, b, c, 0, 0, 0);
}

DEV void stage16(const void* g, void* l) {
#if __has_builtin(__builtin_amdgcn_global_load_lds)
  __builtin_amdgcn_global_load_lds((__attribute__((address_space(1))) void*)g,
                                   (__attribute__((address_space(3))) void*)l, 16, 0, 0);
#else
  *(uint4*)l = *(const uint4*)g;
#endif
}

DEV unsigned pkbf(float a, float b) {
  bf16x2 v = {(__bf16)a, (__bf16)b};
  return __builtin_bit_cast(unsigned, v);
}

// v_permlane32_swap_b32 (orientation verified R3-R5)
DEV void plswap(unsigned& a, unsigned& b) {
#if __has_builtin(__builtin_amdgcn_permlane32_swap)
  auto r = __builtin_amdgcn_permlane32_swap(a, b, false, false);
  a = (unsigned)r[0];
  b = (unsigned)r[1];
#else
  unsigned sa = __shfl_xor((int)a, 32), sb = __shfl_xor((int)b, 32);
  bool hi = ((threadIdx.x & 63) >> 5) != 0;
  unsigned na = hi ? sb : a;
  unsigned nb = hi ? b : sa;
  a = na; b = nb;
#endif
}

// XCD-square swizzle for a 32Mx16N tile grid (nwg=512): XCD x (= lin&7, HW
// round-robin) owns an 8Mx8N square -> 4MB working set, fits one XCD L2.
DEV void xcd_square(int lin, int& mt, int& nt) {
  const int x = lin & 7, i = lin >> 3;   // 64 blocks per XCD
  mt = ((x & 3) << 3) | (i >> 3);        // 0..31
  nt = ((x >> 2) << 3) | (i & 7);        // 0..15
}

// ---------------- fp32->bf16 conversions + RoPE cos/sin table ----------------
__global__ __launch_bounds__(256) void cvt_all(const float* __restrict__ x,
                                               const float* __restrict__ Wq,
                                               const float* __restrict__ Wkv,
                                               const float* __restrict__ Wo,
                                               u16* __restrict__ xb,
                                               u16* __restrict__ wqkv,
                                               u16* __restrict__ wo,
                                               float2* __restrict__ tab) {
  const int blk = blockIdx.x;
  if (blk >= 7168) {   // 256 blocks: 65536-entry rope table (pos 0..2047 x fi 0..31)
    const int idx = (blk - 7168) * 256 + threadIdx.x;
    const int pos = idx >> 5, fi = idx & 31;
    float ang = (float)pos * exp2f((float)fi * -0.415241011860919f);
    float sn, cs;
    sincosf(ang, &sn, &cs);
    tab[idx] = make_float2(cs, sn);
    return;
  }
  const float* src; u16* dst; int base;
  if (blk < 4096)      { src = x;   dst = xb;             base = blk; }
  else if (blk < 5120) { src = Wq;  dst = wqkv;           base = blk - 4096; }
  else if (blk < 6144) { src = Wkv; dst = wqkv + 1048576; base = blk - 5120; }
  else                 { src = Wo;  dst = wo;             base = blk - 6144; }
  const int i = (base * 256 + threadIdx.x) * 4;
  float4 v = *(const float4*)(src + i);
  ushort4 o;
  o.x = f2bf(v.x); o.y = f2bf(v.y); o.z = f2bf(v.z); o.w = f2bf(v.w);
  *(ushort4*)(dst + i) = o;
}

// ---------------- GEMM1 fused with RoPE + LayerNorm epilogue ----------------
// 128x128 tile, BK=64, 2 blocks/CU. T2 LDS XOR-swizzle (stage via pre-swizzled
// source col, read via byte^((row&7)<<4)); counted vmcnt + raw barriers;
// XCD-square block swizzle. (R14's 256x128/1-block-per-CU regressed: the
// cross-block TLP of 2 blocks/CU outweighs halved LDS traffic.)
__global__ __launch_bounds__(256) void gemm_qkv(const u16* __restrict__ A,
                                                const u16* __restrict__ Bm,
                                                const float2* __restrict__ tab,
                                                const float* __restrict__ lng,
                                                const float* __restrict__ lnb,
                                                u16* __restrict__ q_b,
                                                u16* __restrict__ k_b,
                                                u16* __restrict__ vT_b) {
  __shared__ u16 As[2][8192];
  __shared__ u16 Bs[2][8192];
  const int tid = threadIdx.x;
  const int lane = tid & 63;
  const int lo = lane & 15, hi = lane >> 4;
  const int wid = tid >> 6;
  const int wr = wid >> 1, wc = wid & 1;
  int mt, nt;
  xcd_square(blockIdx.y * 16 + blockIdx.x, mt, nt);
  const long m0 = (long)mt * 128;
  const long n0 = (long)nt * 128;

  f32x4 acc[4][4];
  const f32x4 vzero = {0.f, 0.f, 0.f, 0.f};
#pragma unroll
  for (int i = 0; i < 4; ++i)
#pragma unroll
    for (int j = 0; j < 4; ++j) acc[i][j] = vzero;

  const char* Abase = (const char*)(A + m0 * 1024);
  const char* Bbase = (const char*)(Bm + n0 * 1024);

  // prologue: stage K-slab 0 (source col pre-swizzled)
#pragma unroll
  for (int i = 0; i < 4; ++i) {
    int o = (i * 256 + tid) * 16;
    int row = o >> 7, kb = o & 127;
    int sc = kb ^ ((row & 7) << 4);
    stage16(Abase + (long)row * 2048 + sc, (char*)As[0] + o);
    stage16(Bbase + (long)row * 2048 + sc, (char*)Bs[0] + o);
  }

  int cur = 0;
  for (int kt = 0; kt < 16; ++kt) {
    if (kt + 1 < 16) {
      const int kb0 = (kt + 1) * 128;
#pragma unroll
      for (int i = 0; i < 4; ++i) {
        int o = (i * 256 + tid) * 16;
        int row = o >> 7, kb = o & 127;
        int sc = kb ^ ((row & 7) << 4);
        stage16(Abase + (long)row * 2048 + kb0 + sc, (char*)As[cur ^ 1] + o);
        stage16(Bbase + (long)row * 2048 + kb0 + sc, (char*)Bs[cur ^ 1] + o);
      }
      asm volatile("s_waitcnt vmcnt(8)" ::: "memory");
    } else {
      asm volatile("s_waitcnt vmcnt(0)" ::: "memory");
    }
    __builtin_amdgcn_s_barrier();
    __builtin_amdgcn_sched_barrier(0);
#pragma unroll
    for (int ks = 0; ks < 2; ++ks) {
      bf16x8 af[4], bfr[4];
#pragma unroll
      for (int mi = 0; mi < 4; ++mi) {
        const int row = wr * 64 + mi * 16 + lo;
        af[mi] = *(const bf16x8*)((const char*)As[cur] +
                                  ((row * 128 + ks * 64 + hi * 16) ^ ((row & 7) << 4)));
      }
#pragma unroll
      for (int ni = 0; ni < 4; ++ni) {
        const int row = wc * 64 + ni * 16 + lo;
        bfr[ni] = *(const bf16x8*)((const char*)Bs[cur] +
                                   ((row * 128 + ks * 64 + hi * 16) ^ ((row & 7) << 4)));
      }
#pragma unroll
      for (int mi = 0; mi < 4; ++mi)
#pragma unroll
        for (int ni = 0; ni < 4; ++ni)
          acc[mi][ni] = mfma16(af[mi], bfr[ni], acc[mi][ni]);
    }
    __builtin_amdgcn_sched_barrier(0);
    __builtin_amdgcn_s_barrier();
    cur ^= 1;
  }

  // ---- fused epilogue ----
  const int brow = (int)(m0 >> 11);
  const bool isQ = (n0 < 1024);
  const int hbase = isQ ? (int)(n0 >> 6) : (int)((n0 - 1024) >> 6);
  const int h = hbase + wc;
  const int bh = brow * 16 + h;
  float lg[4], lb[4];
  if (!isQ) {
#pragma unroll
    for (int ni = 0; ni < 4; ++ni) {
      lg[ni] = lng[ni * 16 + lo];
      lb[ni] = lnb[ni * 16 + lo];
    }
  }
#pragma unroll
  for (int mi = 0; mi < 4; ++mi) {
    const int pos0 = ((int)m0 & 2047) + wr * 64 + mi * 16 + hi * 4;
    float cs[2][4], sn[2][4];
#pragma unroll
    for (int p = 0; p < 2; ++p)
#pragma unroll
      for (int r = 0; r < 4; ++r) {
        float2 t = tab[(pos0 + r) * 32 + p * 16 + lo];
        cs[p][r] = t.x; sn[p][r] = t.y;
      }
    float o[4][4];
#pragma unroll
    for (int ni = 0; ni < 4; ++ni) {
      const float sgn = (ni < 2) ? -1.f : 1.f;
#pragma unroll
      for (int r = 0; r < 4; ++r)
        o[ni][r] = acc[mi][ni][r] * cs[ni & 1][r] + sgn * acc[mi][ni ^ 2][r] * sn[ni & 1][r];
    }
    if (isQ) {
#pragma unroll
      for (int ni = 0; ni < 4; ++ni)
#pragma unroll
        for (int r = 0; r < 4; ++r)
          q_b[((size_t)bh * 2048 + pos0 + r) * 64 + ni * 16 + lo] =
              f2bf(o[ni][r] * 0.18033688f);   // SCALE*log2(e)
    } else {
      float s1[4], s2[4];
#pragma unroll
      for (int r = 0; r < 4; ++r) {
        s1[r] = o[0][r] + o[1][r] + o[2][r] + o[3][r];
        s2[r] = o[0][r] * o[0][r] + o[1][r] * o[1][r] + o[2][r] * o[2][r] + o[3][r] * o[3][r];
      }
#pragma unroll
      for (int msk = 1; msk < 16; msk <<= 1)
#pragma unroll
        for (int r = 0; r < 4; ++r) {
          s1[r] += __shfl_xor(s1[r], msk);
          s2[r] += __shfl_xor(s2[r], msk);
        }
      u16 kv16[4][4];
#pragma unroll
      for (int r = 0; r < 4; ++r) {
        const float mean = s1[r] * (1.f / 64.f);
        const float var = s2[r] * (1.f / 64.f) - mean * mean;
        const float rstd = rsqrtf(var + 1e-5f);
#pragma unroll
        for (int ni = 0; ni < 4; ++ni) {
          const float lk = (o[ni][r] - mean) * rstd * lg[ni] + lb[ni];
          kv16[ni][r] = f2bf(lk);
          k_b[((size_t)bh * 2048 + pos0 + r) * 64 + ni * 16 + lo] = kv16[ni][r];
        }
      }
#pragma unroll
      for (int ni = 0; ni < 4; ++ni) {
        ushort4 w4 = {kv16[ni][0], kv16[ni][1], kv16[ni][2], kv16[ni][3]};
        *(ushort4*)&vT_b[((size_t)bh * 64 + ni * 16 + lo) * 2048 + pos0] = w4;
      }
    }
  }
}

// ---------------- GEMM2: out = out_all @ Wo^T + bias (128x64 tile) ----------
// T2 swizzle + counted vmcnt + XCD-square; 2 blocks/CU.
__global__ __launch_bounds__(256) void gemm_out(const u16* __restrict__ A,
                                                const u16* __restrict__ Bm,
                                                float* __restrict__ Cf,
                                                const float* __restrict__ bias) {
  __shared__ u16 As[2][8192];
  __shared__ u16 Bs[2][4096];
  const int tid = threadIdx.x;
  const int lane = tid & 63;
  const int lo = lane & 15, hi = lane >> 4;
  const int wid = tid >> 6;
  const int wr = wid >> 1, wc = wid & 1;
  int mt, nt;
  xcd_square(blockIdx.y * 16 + blockIdx.x, mt, nt);
  const long m0 = (long)mt * 128;
  const long n0 = (long)nt * 64;

  f32x4 acc[4][2];
  const f32x4 vzero = {0.f, 0.f, 0.f, 0.f};
#pragma unroll
  for (int i = 0; i < 4; ++i) {
    acc[i][0] = vzero; acc[i][1] = vzero;
  }

  const char* Abase = (const char*)(A + m0 * 1024);
  const char* Bbase = (const char*)(Bm + n0 * 1024);

#pragma unroll
  for (int i = 0; i < 4; ++i) {
    int o = (i * 256 + tid) * 16;
    int row = o >> 7, kb = o & 127;
    int sc = kb ^ ((row & 7) << 4);
    stage16(Abase + (long)row * 2048 + sc, (char*)As[0] + o);
  }
#pragma unroll
  for (int i = 0; i < 2; ++i) {
    int o = (i * 256 + tid) * 16;
    int row = o >> 7, kb = o & 127;
    int sc = kb ^ ((row & 7) << 4);
    stage16(Bbase + (long)row * 2048 + sc, (char*)Bs[0] + o);
  }

  int cur = 0;
  for (int kt = 0; kt < 16; ++kt) {
    if (kt + 1 < 16) {
      const int kb0 = (kt + 1) * 128;
#pragma unroll
      for (int i = 0; i < 4; ++i) {
        int o = (i * 256 + tid) * 16;
        int row = o >> 7, kb = o & 127;
        int sc = kb ^ ((row & 7) << 4);
        stage16(Abase + (long)row * 2048 + kb0 + sc, (char*)As[cur ^ 1] + o);
      }
#pragma unroll
      for (int i = 0; i < 2; ++i) {
        int o = (i * 256 + tid) * 16;
        int row = o >> 7, kb = o & 127;
        int sc = kb ^ ((row & 7) << 4);
        stage16(Bbase + (long)row * 2048 + kb0 + sc, (char*)Bs[cur ^ 1] + o);
      }
      asm volatile("s_waitcnt vmcnt(6)" ::: "memory");
    } else {
      asm volatile("s_waitcnt vmcnt(0)" ::: "memory");
    }
    __builtin_amdgcn_s_barrier();
    __builtin_amdgcn_sched_barrier(0);
#pragma unroll
    for (int ks = 0; ks < 2; ++ks) {
      bf16x8 af[4], bfr[2];
#pragma unroll
      for (int mi = 0; mi < 4; ++mi) {
        const int row = wr * 64 + mi * 16 + lo;
        af[mi] = *(const bf16x8*)((const char*)As[cur] +
                                  ((row * 128 + ks * 64 + hi * 16) ^ ((row & 7) << 4)));
      }
#pragma unroll
      for (int ni = 0; ni < 2; ++ni) {
        const int row = wc * 32 + ni * 16 + lo;
        bfr[ni] = *(const bf16x8*)((const char*)Bs[cur] +
                                   ((row * 128 + ks * 64 + hi * 16) ^ ((row & 7) << 4)));
      }
#pragma unroll
      for (int mi = 0; mi < 4; ++mi)
#pragma unroll
        for (int ni = 0; ni < 2; ++ni)
          acc[mi][ni] = mfma16(af[mi], bfr[ni], acc[mi][ni]);
    }
    __builtin_amdgcn_sched_barrier(0);
    __builtin_amdgcn_s_barrier();
    cur ^= 1;
  }
#pragma unroll
  for (int mi = 0; mi < 4; ++mi)
#pragma unroll
    for (int ni = 0; ni < 2; ++ni) {
      const long col = n0 + wc * 32 + ni * 16 + lo;
      const float bs = bias[col];
#pragma unroll
      for (int r = 0; r < 4; ++r) {
        const long row = m0 + wr * 64 + mi * 16 + hi * 4 + r;
        Cf[row * 1024 + col] = acc[mi][ni][r] + bs;
      }
    }
}

// ---------------- fused flash attention -------------------------------------
// 512 blocks x 256 thr (4 waves, 2 blocks/CU). Block = 128 q rows of one bh;
// wp = 64-q sub-block, half = key-half (in-block k-split, LDS merge).
// Counted vmcnt + raw barriers; all LDS reads hoisted to tile top; fixed-shift
// exp2 softmax; in-register P via cvt_pk + permlane32_swap; T2-swizzled K/V.
__global__ __launch_bounds__(256, 2) void attn_kernel(const u16* __restrict__ q_b,
                                                      const u16* __restrict__ k_b,
                                                      const u16* __restrict__ vT_b,
                                                      u16* __restrict__ out_all) {
  __shared__ __align__(16) char smem[65536];
  __shared__ float ldsLs[2][2][32];
  __shared__ float ldsLi[2][2][32];
  const int tid = threadIdx.x;
  const int wid = tid >> 6, lane = tid & 63;
  const int l31 = lane & 31, lh = lane >> 5;
  const int half = wid >> 1, wp = wid & 1;
  const int bid = blockIdx.x;
  const int xcd = bid & 7, rest = bid >> 3;
  const int bh = (xcd << 2) | (rest & 3);
  const int unit = rest >> 2;
  const int b = bh >> 4, h = bh & 15;
  const bool lat = unit >= 12;
  const int q0b = lat ? 1536 + (unit - 12) * 128 : unit * 128;
  const int q0w = q0b + wp * 64;
  const int nkt_tot = lat ? ((q0b + 128) >> 6) : 24;
  const int nhalf = nkt_tot >> 1;
  const int kt0 = half * nhalf;
  const int wave_kmax = lat ? (q0w + 63) : 1535;
  const char* kg = (const char*)(k_b + (size_t)bh * 2048 * 64);
  const char* vg = (const char*)(vT_b + (size_t)bh * 64 * 2048);
  char* Kbuf0 = smem + half * 32768;
  char* Kbuf1 = Kbuf0 + 8192;
  char* Vbuf0 = Kbuf0 + 16384;
  char* Vbuf1 = Kbuf0 + 24576;
  const f32x16 vzero16 = {0.f,0.f,0.f,0.f,0.f,0.f,0.f,0.f,0.f,0.f,0.f,0.f,0.f,0.f,0.f,0.f};

  bf16x8 qf[2][4];
#pragma unroll
  for (int s = 0; s < 2; ++s) {
    const u16* qrow = q_b + ((size_t)bh * 2048 + q0w + s * 32 + l31) * 64;
#pragma unroll
    for (int ds = 0; ds < 4; ++ds)
      qf[s][ds] = *(const bf16x8*)(qrow + ds * 16 + lh * 8);
  }

  float lsum[2] = {0.f, 0.f};
  f32x16 oacc[2][2];
  oacc[0][0] = vzero16; oacc[0][1] = vzero16;
  oacc[1][0] = vzero16; oacc[1][1] = vzero16;

  const int t127 = tid & 127;

  {
    const int kb0 = kt0 << 6;
#pragma unroll
    for (int i = 0; i < 4; ++i) {
      const int off = t127 * 16 + i * 2048;
      const int row = off >> 7, colb = off & 127;
      const int sc = colb ^ ((row & 7) << 4);
      stage16(kg + (size_t)(kb0 + row) * 128 + sc, Kbuf0 + off);
      stage16(vg + (size_t)row * 4096 + (size_t)(kb0 << 1) + sc, Vbuf0 + off);
    }
  }

  for (int t = 0; t < nhalf; ++t) {
    const int kt = kt0 + t;
    const int k0 = kt << 6;
    const bool more = (t + 1 < nhalf);
    const char* Kc = (t & 1) ? Kbuf1 : Kbuf0;
    const char* Vc = (t & 1) ? Vbuf1 : Vbuf0;
    char* Kn = (t & 1) ? Kbuf0 : Kbuf1;
    char* Vn = (t & 1) ? Vbuf0 : Vbuf1;
    if (more) {
      const int k0n = k0 + 64;
#pragma unroll
      for (int i = 0; i < 4; ++i) {
        const int off = t127 * 16 + i * 2048;
        const int row = off >> 7, colb = off & 127;
        const int sc = colb ^ ((row & 7) << 4);
        stage16(kg + (size_t)(k0n + row) * 128 + sc, Kn + off);
        stage16(vg + (size_t)row * 4096 + (size_t)(k0n << 1) + sc, Vn + off);
      }
      asm volatile("s_waitcnt vmcnt(8)" ::: "memory");
    } else {
      asm volatile("s_waitcnt vmcnt(0)" ::: "memory");
    }
    __builtin_amdgcn_s_barrier();
    __builtin_amdgcn_sched_barrier(0);
    if (k0 <= wave_kmax) {
      const int sw = (l31 & 7) << 4;
      bf16x8 kfr[2][4];
      bf16x8 bv[4][2];
#pragma unroll
      for (int kb = 0; kb < 2; ++kb) {
        const char* kr = Kc + (kb * 32 + l31) * 128;
#pragma unroll
        for (int ds = 0; ds < 4; ++ds)
          kfr[kb][ds] = *(const bf16x8*)(kr + ((ds * 32 + lh * 16) ^ sw));
      }
#pragma unroll
      for (int db = 0; db < 2; ++db) {
        const char* vr = Vc + (db * 32 + l31) * 128;
#pragma unroll
        for (int t4 = 0; t4 < 4; ++t4)
          bv[t4][db] = *(const bf16x8*)(vr + ((t4 * 32 + lh * 16) ^ sw));
      }
      f32x16 s32[2][2];
      __builtin_amdgcn_s_setprio(1);
#pragma unroll
      for (int kb = 0; kb < 2; ++kb)
#pragma unroll
        for (int s = 0; s < 2; ++s) {
          f32x16 acc = vzero16;
#pragma unroll
          for (int ds = 0; ds < 4; ++ds)
            acc = mfma32(kfr[kb][ds], qf[s][ds], acc);
          s32[s][kb] = acc;
        }
      __builtin_amdgcn_s_setprio(0);
      unsigned w[2][16];
#pragma unroll
      for (int s = 0; s < 2; ++s) {
        if (lat && (k0 + 63 > q0w + s * 32)) {
          const int qg = q0w + s * 32 + l31;
#pragma unroll
          for (int kb = 0; kb < 2; ++kb)
#pragma unroll
            for (int r = 0; r < 16; ++r) {
              const int key = k0 + kb * 32 + (r & 3) + 8 * (r >> 2) + 4 * lh;
              if (key > qg) s32[s][kb][r] = -1e30f;
            }
        }
#pragma unroll
        for (int kb = 0; kb < 2; ++kb) {
          float p[16];
#pragma unroll
          for (int r = 0; r < 16; ++r) {
            p[r] = fexp2(s32[s][kb][r]);
            lsum[s] += p[r];
          }
#pragma unroll
          for (int m = 0; m < 8; ++m) w[s][kb * 8 + m] = pkbf(p[2 * m], p[2 * m + 1]);
        }
      }
#pragma unroll
      for (int t4 = 0; t4 < 4; ++t4) {
        const int g = t4 * 4;
        union { unsigned uw[4]; bf16x8 v; } A[2];
#pragma unroll
        for (int s = 0; s < 2; ++s) {
          plswap(w[s][g], w[s][g + 2]);
          plswap(w[s][g + 1], w[s][g + 3]);
          A[s].uw[0] = w[s][g];     A[s].uw[1] = w[s][g + 1];
          A[s].uw[2] = w[s][g + 2]; A[s].uw[3] = w[s][g + 3];
        }
        __builtin_amdgcn_s_setprio(1);
#pragma unroll
        for (int db = 0; db < 2; ++db) {
          oacc[0][db] = mfma32(A[0].v, bv[t4][db], oacc[0][db]);
          oacc[1][db] = mfma32(A[1].v, bv[t4][db], oacc[1][db]);
        }
        __builtin_amdgcn_s_setprio(0);
      }
    }
    __builtin_amdgcn_sched_barrier(0);
    __builtin_amdgcn_s_barrier();
  }

  float* mergeO = (float*)smem + (size_t)wp * 4096;
  if (half == 1) {
#pragma unroll
    for (int s = 0; s < 2; ++s) {
      float ls = lsum[s] + __shfl_xor(lsum[s], 32);
      if (lh == 0) ldsLs[wp][s][l31] = ls;
#pragma unroll
      for (int db = 0; db < 2; ++db)
#pragma unroll
        for (int r = 0; r < 16; ++r) {
          const int qv = (r & 3) + 8 * (r >> 2) + 4 * lh;
          mergeO[(s * 32 + qv) * 64 + db * 32 + l31] = oacc[s][db][r];
        }
    }
  }
  __syncthreads();
  if (half == 0) {
#pragma unroll
    for (int s = 0; s < 2; ++s) {
      float ls = lsum[s] + __shfl_xor(lsum[s], 32) + ldsLs[wp][s][l31];
      if (lh == 0) ldsLi[wp][s][l31] = 1.f / ls;
    }
    const int orow0 = lat ? (q0w - 1536) : (512 + q0w);
#pragma unroll
    for (int s = 0; s < 2; ++s)
#pragma unroll
      for (int db = 0; db < 2; ++db)
#pragma unroll
        for (int r = 0; r < 16; ++r) {
          const int qv = (r & 3) + 8 * (r >> 2) + 4 * lh;
          const float o = oacc[s][db][r] + mergeO[(s * 32 + qv) * 64 + db * 32 + l31];
          out_all[((size_t)b * 2048 + orow0 + s * 32 + qv) * 1024 + h * 64 + db * 32 + l31] =
              f2bf(o * ldsLi[wp][s][qv]);
        }
  }
}

extern "C" void kernel_launch(void* const* d_in, const int* in_sizes, int n_in,
                              void* d_out, int out_size, void* d_ws, size_t ws_size,
                              hipStream_t stream) {
  const float* x    = (const float*)d_in[0];
  const float* Wq   = (const float*)d_in[1];
  const float* Wkv  = (const float*)d_in[2];
  const float* Wo   = (const float*)d_in[3];
  const float* bo   = (const float*)d_in[4];
  const float* ln_g = (const float*)d_in[5];
  const float* ln_b = (const float*)d_in[6];
  float* out = (float*)d_out;
  char* ws = (char*)d_ws;

  u16*    xb      = (u16*)(ws + 0);                     // 8MB (dead after gemm_qkv)
  u16*    out_all = (u16*)(ws + 0);                     // 8MB (attn -> gemm_out)
  u16*    wqkv_b  = (u16*)(ws + (size_t)(8u << 20));    // 4MB
  u16*    wo_b    = (u16*)(ws + (size_t)(12u << 20));   // 2MB
  float2* tab     = (float2*)(ws + (size_t)(14u << 20));// 512KB rope table
  u16*    q_b     = (u16*)(ws + (size_t)(15u << 20));   // 8MB
  u16*    k_b     = (u16*)(ws + (size_t)(23u << 20));   // 8MB
  u16*    vT_b    = (u16*)(ws + (size_t)(31u << 20));   // 8MB

  cvt_all<<<7424, 256, 0, stream>>>(x, Wq, Wkv, Wo, xb, wqkv_b, wo_b, tab);
  gemm_qkv<<<dim3(16, 32), 256, 0, stream>>>(xb, wqkv_b, tab, ln_g, ln_b,
                                             q_b, k_b, vT_b);
  attn_kernel<<<512, 256, 0, stream>>>(q_b, k_b, vT_b, out_all);
  gemm_out<<<dim3(16, 32), 256, 0, stream>>>(out_all, wo_b, out, bo);
}